// Round 3
// baseline (224.692 us; speedup 1.0000x reference)
//
#include <hip/hip_runtime.h>

// BehaviorFluidFlow — wave-per-row, all-register, zero-barrier formulation.
//
// Facts used (validated absmax=0.0 in R1/R2):
//   * all interaction is roll(+/-1) along W; becomes_right[w] == becomes_left[w+sh]
//   * blend coefficients a,b in {0,1} are channel-independent:
//       new[w] = (1-a)(1-b)*old[w] + a*old[w-sh] + b*old[w+sh]
//     so each pixel's value is a sum of source pixels (usually exactly one).
// Design: 1 wave (64 lanes) owns one (b,h) row; 8 contiguous px per lane in
// registers. Decision channels tracked exactly: dens/fm as f32, the 5 fluid
// one-hots + gravity as 4-bit counters packed in a u32 (values are small
// exact ints; sums add counters). The 12 passive channels (9 non-fluid elems
// + 3 rest) are reconstructed at the end from per-pixel provenance slots
// (up to 6 source indices, exact fp summation order preserved). Neighbor
// exchange is 12 __shfl per pass. No __syncthreads, no LDS arrays.

#define CCH 20
#define BHW ((size_t)4194304)   // 16*512*512
#define CH  ((size_t)262144)    // 512*512

#define LD8(dst, p) { const float4* _q=(const float4*)(p); float4 _x=_q[0],_y=_q[1]; \
  dst[0]=_x.x;dst[1]=_x.y;dst[2]=_x.z;dst[3]=_x.w;dst[4]=_y.x;dst[5]=_y.y;dst[6]=_y.z;dst[7]=_y.w; }
#define ST8(p, v) { float4* _q=(float4*)(p); _q[0]=make_float4(v[0],v[1],v[2],v[3]); \
  _q[1]=make_float4(v[4],v[5],v[6],v[7]); }

__global__ __launch_bounds__(256) void fluid_wave_kernel(
    const float* __restrict__ world_in,
    const float* __restrict__ rm_in,
    const float* __restrict__ ri_in,
    const float* __restrict__ re_in,
    const float* __restrict__ vf_in,
    const float* __restrict__ dg_in,
    float* __restrict__ out)
{
    const int lane = threadIdx.x & 63;
    const int row  = (blockIdx.x << 2) + (threadIdx.x >> 6);   // b*512 + h
    const int b    = row >> 9;
    const int h    = row & 511;
    const int px0  = lane << 3;

    const size_t srow = (size_t)row * 512;                      // scalar tensors
    const size_t wrow = (((size_t)b * CCH) * 512 + h) * 512;    // world ch 0 row
    const size_t vrow0 = (((size_t)b * 2) * 512 + h) * 512;
    const size_t vrow1 = vrow0 + CH;

    // ---- passthrough copies (issued first, overlap with everything) ----
    float t[8];
    LD8(t, ri_in + srow + px0); ST8(out + 21*BHW + srow + px0, t);
    LD8(t, re_in + srow + px0); ST8(out + 22*BHW + srow + px0, t);
    LD8(t, vf_in + vrow0 + px0); ST8(out + 23*BHW + vrow0 + px0, t);
    LD8(t, vf_in + vrow1 + px0); ST8(out + 23*BHW + vrow1 + px0, t);

    // ---- load decision state ----
    float rm[8], dgv[8], dens[8], fm[8], nf[8];
    uint32_t code[8], sA[8], sB[8];
    LD8(rm,  rm_in + srow + px0);  ST8(out + 20*BHW + srow + px0, rm);
    LD8(dgv, dg_in + srow + px0);  ST8(out + 25*BHW + srow + px0, dgv);
    LD8(dens, world_in + wrow + 14*CH + px0);
    LD8(fm,   world_in + wrow + 16*CH + px0);

    uint32_t ndgm = 0;
    #pragma unroll
    for (int j = 0; j < 8; ++j) ndgm |= (uint32_t)(dgv[j] <= 0.0f) << j;

    LD8(t, world_in + wrow + 15*CH + px0);   // gravity
    #pragma unroll
    for (int j = 0; j < 8; ++j) code[j] = (uint32_t)(t[j] == 1.0f) << 20;
    LD8(t, world_in + wrow +  0*CH + px0);
    #pragma unroll
    for (int j = 0; j < 8; ++j) code[j] |= (uint32_t)(t[j] == 1.0f);
    LD8(t, world_in + wrow +  3*CH + px0);
    #pragma unroll
    for (int j = 0; j < 8; ++j) code[j] |= (uint32_t)(t[j] == 1.0f) << 4;
    LD8(t, world_in + wrow +  4*CH + px0);
    #pragma unroll
    for (int j = 0; j < 8; ++j) code[j] |= (uint32_t)(t[j] == 1.0f) << 8;
    LD8(t, world_in + wrow + 10*CH + px0);
    #pragma unroll
    for (int j = 0; j < 8; ++j) code[j] |= (uint32_t)(t[j] == 1.0f) << 12;
    LD8(t, world_in + wrow + 11*CH + px0);
    #pragma unroll
    for (int j = 0; j < 8; ++j) code[j] |= (uint32_t)(t[j] == 1.0f) << 16;

    #pragma unroll
    for (int j = 0; j < 8; ++j) {
        sA[j] = 1u | ((uint32_t)(px0 + j) << 4);  // cnt=1, src0=own index
        sB[j] = 0u;
        nf[j] = 0.0f;
    }

    const int lft = (lane + 63) & 63, rgt = (lane + 1) & 63;

    // ---- 10 passes: (elem in {0,3,4,10,11}) x (fall_left, fall_right) ----
    #pragma unroll 1
    for (int ei = 0; ei < 5; ++ei) {
        const int sft = ei * 4;               // nibble slot of this elem
        #pragma unroll
        for (int fi = 0; fi < 2; ++fi) {
            const bool  fl = (fi == 0);       // fall_left first
            const float k  = fl ? 2.0f : -2.0f;

            // edge state of OLD values from neighbor lanes
            const float dL = __shfl(dens[7], lft), dR = __shfl(dens[0], rgt);
            const float fL = __shfl(fm[7],  lft), fR = __shfl(fm[0],  rgt);
            const uint32_t cL = (uint32_t)__shfl((int)code[7], lft);
            const uint32_t cR = (uint32_t)__shfl((int)code[0], rgt);
            const uint32_t AL = (uint32_t)__shfl((int)sA[7], lft);
            const uint32_t AR = (uint32_t)__shfl((int)sA[0], rgt);
            const uint32_t BL = (uint32_t)__shfl((int)sB[7], lft);
            const uint32_t BR = (uint32_t)__shfl((int)sB[0], rgt);

            // a-bits: becomes_left[w], wm = w - sh
            uint32_t am = 0;
            #pragma unroll
            for (int j = 0; j < 8; ++j) {
                float dwm; uint32_t cwm;
                if (fl) { dwm = j ? dens[j-1] : dL;       cwm = j ? code[j-1] : cL; }
                else    { dwm = (j<7) ? dens[j+1] : dR;   cwm = (j<7) ? code[j+1] : cR; }
                const bool fd  = ((rm[j] + fm[j]) + nf[j]) > 0.5f;
                const bool imf = fl ? fd : !fd;
                const bool a = imf
                    && (((code[j] >> sft) & 15u) == 1u)      // is_element
                    && (((ndgm >> j) & 1u) != 0u)            // not_did_gravity
                    && ((dens[j] - dwm) > 0.0f)              // density lower at wm
                    && (((cwm    >> 20) & 15u) == 1u)        // gravity at wm
                    && (((code[j] >> 20) & 15u) == 1u);      // gravity at w
                am |= (uint32_t)a << j;
            }

            // b-bits: becomes_right[w] = a[w+sh]
            const uint32_t aLm = (uint32_t)__shfl((int)am, lft);
            const uint32_t aRm = (uint32_t)__shfl((int)am, rgt);
            const uint32_t bm = fl ? ((am >> 1) | ((aRm & 1u) << 7))
                                   : (((am << 1) & 0xFFu) | ((aLm >> 7) & 1u));

            // blend: new[w] = sel(old[w-sh], old[w], old[w+sh]) (or sum if a&b)
            float prD = dL, prF = fL;                    // old[j-1]
            uint32_t prC = cL, prA = AL, prB = BL;
            #pragma unroll
            for (int j = 0; j < 8; ++j) {
                const float    ahD = (j<7) ? dens[j+1] : dR;   // old[j+1]
                const float    ahF = (j<7) ? fm[j+1]   : fR;
                const uint32_t ahC = (j<7) ? code[j+1] : cR;
                const uint32_t ahA = (j<7) ? sA[j+1]   : AR;
                const uint32_t ahB = (j<7) ? sB[j+1]   : BR;
                const float    wmD = fl ? prD : ahD, wpD = fl ? ahD : prD;
                const float    wmF = fl ? prF : ahF, wpF = fl ? ahF : prF;
                const uint32_t wmC = fl ? prC : ahC, wpC = fl ? ahC : prC;
                const uint32_t wmA = fl ? prA : ahA, wpA = fl ? ahA : prA;
                const uint32_t wmB = fl ? prB : ahB, wpB = fl ? ahB : prB;
                const bool a  = (am >> j) & 1u;
                const bool bb = (bm >> j) & 1u;
                if (bb) nf[j] += k;
                prD = dens[j]; prF = fm[j]; prC = code[j]; prA = sA[j]; prB = sB[j];
                if (a & bb) {            // rare double-swap: values SUM
                    dens[j] = wmD + wpD; fm[j] = wmF + wpF; code[j] = wmC + wpC;
                    const uint32_t c1 = wmA & 15u, c2 = wpA & 15u;
                    const uint64_t l1 = ((uint64_t)(wmA >> 4)) | ((uint64_t)wmB << 27);
                    const uint64_t l2 = ((uint64_t)(wpA >> 4)) | ((uint64_t)wpB << 27);
                    uint32_t cnt = c1 + c2; if (cnt > 6u) cnt = 6u;
                    const uint64_t all = l1 | (l2 << (9u * c1));
                    sA[j] = cnt | ((uint32_t)(all & 0x7FFFFFFull) << 4);
                    sB[j] = (uint32_t)((all >> 27) & 0x7FFFFFFull);
                } else if (a) {
                    dens[j] = wmD; fm[j] = wmF; code[j] = wmC; sA[j] = wmA; sB[j] = wmB;
                } else if (bb) {
                    dens[j] = wpD; fm[j] = wpF; code[j] = wpC; sA[j] = wpA; sB[j] = wpB;
                }
            }
        }
    }

    // ---- outputs: tracked channels ----
    float o[8];
    #pragma unroll
    for (int j=0;j<8;++j) o[j] = (float)( code[j]        & 15u); ST8(out + wrow +  0*CH + px0, o);
    #pragma unroll
    for (int j=0;j<8;++j) o[j] = (float)((code[j] >>  4) & 15u); ST8(out + wrow +  3*CH + px0, o);
    #pragma unroll
    for (int j=0;j<8;++j) o[j] = (float)((code[j] >>  8) & 15u); ST8(out + wrow +  4*CH + px0, o);
    #pragma unroll
    for (int j=0;j<8;++j) o[j] = (float)((code[j] >> 12) & 15u); ST8(out + wrow + 10*CH + px0, o);
    #pragma unroll
    for (int j=0;j<8;++j) o[j] = (float)((code[j] >> 16) & 15u); ST8(out + wrow + 11*CH + px0, o);
    #pragma unroll
    for (int j=0;j<8;++j) o[j] = (float)((code[j] >> 20) & 15u); ST8(out + wrow + 15*CH + px0, o);
    ST8(out + wrow + 14*CH + px0, dens);
    ST8(out + wrow + 16*CH + px0, nf);

    // ---- passive channels via provenance gather ----
    const int GC[12] = {1,2,5,6,7,8,9,12,13,17,18,19};
    #pragma unroll
    for (int g = 0; g < 12; ++g) {
        const float* src = world_in + wrow + (size_t)GC[g] * CH;
        float v[8];
        #pragma unroll
        for (int j = 0; j < 8; ++j) {
            const uint32_t A = sA[j], c = A & 15u;
            float x = src[(A >> 4) & 511u];
            if (c > 1u) { x += src[(A >> 13) & 511u];
              if (c > 2u) { x += src[(A >> 22) & 511u];
                if (c > 3u) { const uint32_t Bv = sB[j]; x += src[Bv & 511u];
                  if (c > 4u) { x += src[(Bv >> 9) & 511u];
                    if (c > 5u) x += src[(Bv >> 18) & 511u]; } } } }
            v[j] = x;
        }
        ST8(out + wrow + (size_t)GC[g] * CH + px0, v);
    }
}

extern "C" void kernel_launch(void* const* d_in, const int* in_sizes, int n_in,
                              void* d_out, int out_size, void* d_ws, size_t ws_size,
                              hipStream_t stream) {
    const float* world = (const float*)d_in[0];
    const float* rm    = (const float*)d_in[1];
    const float* ri    = (const float*)d_in[2];
    const float* re    = (const float*)d_in[3];
    const float* vf    = (const float*)d_in[4];
    const float* dg    = (const float*)d_in[5];
    float* out = (float*)d_out;

    dim3 grid(2048), block(256);   // 4 rows per block, 1 wave per row
    fluid_wave_kernel<<<grid, block, 0, stream>>>(world, rm, ri, re, vf, dg, out);
}

// Round 4
// 181.199 us; speedup vs baseline: 1.2400x; 1.2400x over previous
//
#include <hip/hip_runtime.h>

// BehaviorFluidFlow — wave-per-row, all-register, zero-barrier formulation.
// R4: same 10-pass register loop as R3 (validated absmax=0.0), but the
// passive-channel reconstruction now goes through a per-wave LDS staging
// buffer with coalesced float4 global I/O, instead of 96 scalar global
// gathers (R3's regression).
//
//   * all interaction is roll(+/-1) along W; becomes_right[w] == becomes_left[w+sh]
//   * blend coeffs a,b in {0,1} channel-independent -> each pixel is a sum of
//     source pixels (usually exactly one). Track decision channels exactly
//     (dens/fm f32, one-hots+gravity as nibble counters), record provenance
//     (up to 6 sources) and apply it to the 12 passive channels at the end.

#define CCH 20
#define BHW ((size_t)4194304)   // 16*512*512
#define CH  ((size_t)262144)    // 512*512

#define LD8(dst, p) { const float4* _q=(const float4*)(p); float4 _x=_q[0],_y=_q[1]; \
  dst[0]=_x.x;dst[1]=_x.y;dst[2]=_x.z;dst[3]=_x.w;dst[4]=_y.x;dst[5]=_y.y;dst[6]=_y.z;dst[7]=_y.w; }
#define ST8(p, v) { float4* _q=(float4*)(p); _q[0]=make_float4(v[0],v[1],v[2],v[3]); \
  _q[1]=make_float4(v[4],v[5],v[6],v[7]); }

__global__ __launch_bounds__(256) void fluid_wave_kernel(
    const float* __restrict__ world_in,
    const float* __restrict__ rm_in,
    const float* __restrict__ ri_in,
    const float* __restrict__ re_in,
    const float* __restrict__ vf_in,
    const float* __restrict__ dg_in,
    float* __restrict__ out)
{
    // per-wave double-buffered staging row: 512 + 16 pad (s(w)=w+(w>>5) <= 526)
    __shared__ float s_g[4][2][528];

    const int lane = threadIdx.x & 63;
    const int wv   = threadIdx.x >> 6;
    const int row  = (blockIdx.x << 2) + wv;   // b*512 + h
    const int b    = row >> 9;
    const int h    = row & 511;
    const int px0  = lane << 3;

    const size_t srow  = (size_t)row * 512;
    const size_t wrow  = (((size_t)b * CCH) * 512 + h) * 512;
    const size_t vrow0 = (((size_t)b * 2) * 512 + h) * 512;
    const size_t vrow1 = vrow0 + CH;

    // ---- passthrough copies (issued first, overlap with everything) ----
    float t[8];
    LD8(t, ri_in + srow + px0);  ST8(out + 21*BHW + srow + px0, t);
    LD8(t, re_in + srow + px0);  ST8(out + 22*BHW + srow + px0, t);
    LD8(t, vf_in + vrow0 + px0); ST8(out + 23*BHW + vrow0 + px0, t);
    LD8(t, vf_in + vrow1 + px0); ST8(out + 23*BHW + vrow1 + px0, t);

    // ---- load decision state ----
    float rm[8], dgv[8], dens[8], fm[8], nf[8];
    uint32_t code[8], sA[8], sB[8];
    LD8(rm,  rm_in + srow + px0);  ST8(out + 20*BHW + srow + px0, rm);
    LD8(dgv, dg_in + srow + px0);  ST8(out + 25*BHW + srow + px0, dgv);
    LD8(dens, world_in + wrow + 14*CH + px0);
    LD8(fm,   world_in + wrow + 16*CH + px0);

    uint32_t ndgm = 0;
    #pragma unroll
    for (int j = 0; j < 8; ++j) ndgm |= (uint32_t)(dgv[j] <= 0.0f) << j;

    LD8(t, world_in + wrow + 15*CH + px0);   // gravity
    #pragma unroll
    for (int j = 0; j < 8; ++j) code[j] = (uint32_t)(t[j] == 1.0f) << 20;
    LD8(t, world_in + wrow +  0*CH + px0);
    #pragma unroll
    for (int j = 0; j < 8; ++j) code[j] |= (uint32_t)(t[j] == 1.0f);
    LD8(t, world_in + wrow +  3*CH + px0);
    #pragma unroll
    for (int j = 0; j < 8; ++j) code[j] |= (uint32_t)(t[j] == 1.0f) << 4;
    LD8(t, world_in + wrow +  4*CH + px0);
    #pragma unroll
    for (int j = 0; j < 8; ++j) code[j] |= (uint32_t)(t[j] == 1.0f) << 8;
    LD8(t, world_in + wrow + 10*CH + px0);
    #pragma unroll
    for (int j = 0; j < 8; ++j) code[j] |= (uint32_t)(t[j] == 1.0f) << 12;
    LD8(t, world_in + wrow + 11*CH + px0);
    #pragma unroll
    for (int j = 0; j < 8; ++j) code[j] |= (uint32_t)(t[j] == 1.0f) << 16;

    // prefetch first passive channel (hides HBM latency behind the pass loop)
    float cur[8];
    LD8(cur, world_in + wrow + 1*CH + px0);

    #pragma unroll
    for (int j = 0; j < 8; ++j) {
        sA[j] = 1u | ((uint32_t)(px0 + j) << 4);  // cnt=1, src0=own index
        sB[j] = 0u;
        nf[j] = 0.0f;
    }

    const int lft = (lane + 63) & 63, rgt = (lane + 1) & 63;

    // ---- 10 passes: (elem in {0,3,4,10,11}) x (fall_left, fall_right) ----
    #pragma unroll 1
    for (int ei = 0; ei < 5; ++ei) {
        const int sft = ei * 4;               // nibble slot of this elem
        #pragma unroll
        for (int fi = 0; fi < 2; ++fi) {
            const bool  fl = (fi == 0);       // fall_left first
            const float k  = fl ? 2.0f : -2.0f;

            // edge state of OLD values from neighbor lanes
            const float dL = __shfl(dens[7], lft), dR = __shfl(dens[0], rgt);
            const float fL = __shfl(fm[7],  lft), fR = __shfl(fm[0],  rgt);
            const uint32_t cL = (uint32_t)__shfl((int)code[7], lft);
            const uint32_t cR = (uint32_t)__shfl((int)code[0], rgt);
            const uint32_t AL = (uint32_t)__shfl((int)sA[7], lft);
            const uint32_t AR = (uint32_t)__shfl((int)sA[0], rgt);
            const uint32_t BL = (uint32_t)__shfl((int)sB[7], lft);
            const uint32_t BR = (uint32_t)__shfl((int)sB[0], rgt);

            // a-bits: becomes_left[w], wm = w - sh
            uint32_t am = 0;
            #pragma unroll
            for (int j = 0; j < 8; ++j) {
                float dwm; uint32_t cwm;
                if (fl) { dwm = j ? dens[j-1] : dL;       cwm = j ? code[j-1] : cL; }
                else    { dwm = (j<7) ? dens[j+1] : dR;   cwm = (j<7) ? code[j+1] : cR; }
                const bool fd  = ((rm[j] + fm[j]) + nf[j]) > 0.5f;
                const bool imf = fl ? fd : !fd;
                const bool a = imf
                    && (((code[j] >> sft) & 15u) == 1u)      // is_element
                    && (((ndgm >> j) & 1u) != 0u)            // not_did_gravity
                    && ((dens[j] - dwm) > 0.0f)              // density lower at wm
                    && (((cwm    >> 20) & 15u) == 1u)        // gravity at wm
                    && (((code[j] >> 20) & 15u) == 1u);      // gravity at w
                am |= (uint32_t)a << j;
            }

            // b-bits: becomes_right[w] = a[w+sh]
            const uint32_t aLm = (uint32_t)__shfl((int)am, lft);
            const uint32_t aRm = (uint32_t)__shfl((int)am, rgt);
            const uint32_t bm = fl ? ((am >> 1) | ((aRm & 1u) << 7))
                                   : (((am << 1) & 0xFFu) | ((aLm >> 7) & 1u));

            // blend: new[w] = sel(old[w-sh], old[w], old[w+sh]) (or sum if a&b)
            float prD = dL, prF = fL;                    // old[j-1]
            uint32_t prC = cL, prA = AL, prB = BL;
            #pragma unroll
            for (int j = 0; j < 8; ++j) {
                const float    ahD = (j<7) ? dens[j+1] : dR;   // old[j+1]
                const float    ahF = (j<7) ? fm[j+1]   : fR;
                const uint32_t ahC = (j<7) ? code[j+1] : cR;
                const uint32_t ahA = (j<7) ? sA[j+1]   : AR;
                const uint32_t ahB = (j<7) ? sB[j+1]   : BR;
                const float    wmD = fl ? prD : ahD, wpD = fl ? ahD : prD;
                const float    wmF = fl ? prF : ahF, wpF = fl ? ahF : prF;
                const uint32_t wmC = fl ? prC : ahC, wpC = fl ? ahC : prC;
                const uint32_t wmA = fl ? prA : ahA, wpA = fl ? ahA : prA;
                const uint32_t wmB = fl ? prB : ahB, wpB = fl ? ahB : prB;
                const bool a  = (am >> j) & 1u;
                const bool bb = (bm >> j) & 1u;
                if (bb) nf[j] += k;
                prD = dens[j]; prF = fm[j]; prC = code[j]; prA = sA[j]; prB = sB[j];
                if (a & bb) {            // rare double-swap: values SUM
                    dens[j] = wmD + wpD; fm[j] = wmF + wpF; code[j] = wmC + wpC;
                    const uint32_t c1 = wmA & 15u, c2 = wpA & 15u;
                    const uint64_t l1 = ((uint64_t)(wmA >> 4)) | ((uint64_t)wmB << 27);
                    const uint64_t l2 = ((uint64_t)(wpA >> 4)) | ((uint64_t)wpB << 27);
                    uint32_t cnt = c1 + c2; if (cnt > 6u) cnt = 6u;
                    const uint64_t all = l1 | (l2 << (9u * c1));
                    sA[j] = cnt | ((uint32_t)(all & 0x7FFFFFFull) << 4);
                    sB[j] = (uint32_t)((all >> 27) & 0x7FFFFFFull);
                } else if (a) {
                    dens[j] = wmD; fm[j] = wmF; code[j] = wmC; sA[j] = wmA; sB[j] = wmB;
                } else if (bb) {
                    dens[j] = wpD; fm[j] = wpF; code[j] = wpC; sA[j] = wpA; sB[j] = wpB;
                }
            }
        }
    }

    // ---- outputs: tracked channels (frees code[] before the gather) ----
    float o[8];
    #pragma unroll
    for (int j=0;j<8;++j) o[j] = (float)( code[j]        & 15u); ST8(out + wrow +  0*CH + px0, o);
    #pragma unroll
    for (int j=0;j<8;++j) o[j] = (float)((code[j] >>  4) & 15u); ST8(out + wrow +  3*CH + px0, o);
    #pragma unroll
    for (int j=0;j<8;++j) o[j] = (float)((code[j] >>  8) & 15u); ST8(out + wrow +  4*CH + px0, o);
    #pragma unroll
    for (int j=0;j<8;++j) o[j] = (float)((code[j] >> 12) & 15u); ST8(out + wrow + 10*CH + px0, o);
    #pragma unroll
    for (int j=0;j<8;++j) o[j] = (float)((code[j] >> 16) & 15u); ST8(out + wrow + 11*CH + px0, o);
    #pragma unroll
    for (int j=0;j<8;++j) o[j] = (float)((code[j] >> 20) & 15u); ST8(out + wrow + 15*CH + px0, o);
    ST8(out + wrow + 14*CH + px0, dens);
    ST8(out + wrow + 16*CH + px0, nf);

    // ---- passive channels: LDS-staged provenance apply, double-buffered ----
    // swizzle s(w) = w + (w>>5): 2-way bank aliasing (free) for stride-8 lanes
    uint32_t multi = 0;
    int sidx0[8];
    #pragma unroll
    for (int j = 0; j < 8; ++j) {
        const uint32_t p = (sA[j] >> 4) & 511u;
        sidx0[j] = (int)(p + (p >> 5));
        multi |= (uint32_t)((sA[j] & 15u) > 1u) << j;
    }
    const int pad = lane >> 2;   // (px0+j)>>5, const for j<8

    static const int GCv[12] = {1,2,5,6,7,8,9,12,13,17,18,19};
    float nxt[8];
    #pragma unroll
    for (int g = 0; g < 12; ++g) {
        float* buf = &s_g[wv][g & 1][0];
        #pragma unroll
        for (int j = 0; j < 8; ++j) buf[px0 + pad + j] = cur[j];
        if (g < 11) { LD8(nxt, world_in + wrow + (size_t)GCv[g + 1] * CH + px0); }
        float v[8];
        #pragma unroll
        for (int j = 0; j < 8; ++j) v[j] = buf[sidx0[j]];
        if (multi) {   // rare multi-source pixels (a&b double-swap history)
            #pragma unroll
            for (int j = 0; j < 8; ++j) if ((multi >> j) & 1u) {
                const uint32_t A = sA[j], c = A & 15u, Bv = sB[j];
                uint32_t p1 = (A >> 13) & 511u; float x = v[j] + buf[p1 + (p1 >> 5)];
                if (c > 2u) { uint32_t p2 = (A >> 22) & 511u; x += buf[p2 + (p2 >> 5)];
                  if (c > 3u) { uint32_t p3 = Bv & 511u; x += buf[p3 + (p3 >> 5)];
                    if (c > 4u) { uint32_t p4 = (Bv >> 9) & 511u; x += buf[p4 + (p4 >> 5)];
                      if (c > 5u) { uint32_t p5 = (Bv >> 18) & 511u; x += buf[p5 + (p5 >> 5)]; } } } }
                v[j] = x;
            }
        }
        ST8(out + wrow + (size_t)GCv[g] * CH + px0, v);
        #pragma unroll
        for (int j = 0; j < 8; ++j) cur[j] = nxt[j];
    }
}

extern "C" void kernel_launch(void* const* d_in, const int* in_sizes, int n_in,
                              void* d_out, int out_size, void* d_ws, size_t ws_size,
                              hipStream_t stream) {
    const float* world = (const float*)d_in[0];
    const float* rm    = (const float*)d_in[1];
    const float* ri    = (const float*)d_in[2];
    const float* re    = (const float*)d_in[3];
    const float* vf    = (const float*)d_in[4];
    const float* dg    = (const float*)d_in[5];
    float* out = (float*)d_out;

    dim3 grid(2048), block(256);   // 4 rows per block, 1 wave per row
    fluid_wave_kernel<<<grid, block, 0, stream>>>(world, rm, ri, re, vf, dg, out);
}